// Round 1
// baseline (232.336 us; speedup 1.0000x reference)
//
#include <hip/hip_runtime.h>
#include <hip/hip_bf16.h>

// SpectralConv2d (FNO): B=8, C_IN=C_OUT=32, H=W=256, modes 32x32 (low kx) + 32x32 (high kx), ky 0..31.
// Pipeline: rFFT(w) as bf16-MFMA GEMM -> FFT(h) fp32 w/ rotation-recurrence twiddles (ky-split x4)
//           -> complex mix -> iFFT(h) fp32 recurrence (ky-split x4, writes bf16)
//           -> irFFT(w)+bias as bf16-MFMA GEMM.

#define BD 256

typedef __attribute__((ext_vector_type(8))) short bf16x8;
typedef __attribute__((ext_vector_type(4))) float f32x4;

__device__ inline unsigned short f2bf(float f) {
    union { float f; unsigned u; } v; v.f = f;
    unsigned r = v.u + 0x7FFF + ((v.u >> 16) & 1);   // RNE
    return (unsigned short)(r >> 16);
}

// Merged setup: block 0 -> twiddle table; blocks 1..128 -> BmA/BmC; blocks 129.. -> wpack.
// tw[t] = (cos, sin)(2pi t/256)
// BmA[n][w] (n=2ky+c): c=0 -> cos(2pi ky w/256), c=1 -> -sin    [64][256]
// BmC[w][k] (k=2ky+c): c=0 -> cos, c=1 -> -sin                  [256][64]
// wpack[(m*32+ky)*1024 + i*32 + o] = w[i][o][m'][ky] * c_ky / 65536 (complex)
__global__ void k_setup(float2* __restrict__ tw,
                        unsigned short* __restrict__ BmA, unsigned short* __restrict__ BmC,
                        const float* __restrict__ w1r, const float* __restrict__ w1i,
                        const float* __restrict__ w2r, const float* __restrict__ w2i,
                        float2* __restrict__ wpack) {
    int b = blockIdx.x, t = threadIdx.x;
    if (b == 0) {
        double th = 6.283185307179586476925286766559 * (double)t / 256.0;
        tw[t] = make_float2((float)cos(th), (float)sin(th));
    } else if (b <= 128) {
        int idx = (b - 1) * BD + t;    // 0..32767
        if (idx < 16384) {
            int w = idx & 255, n = idx >> 8;
            int ky = n >> 1, c = n & 1;
            double th = 6.283185307179586476925286766559 * (double)((ky * w) & 255) / 256.0;
            BmA[idx] = f2bf(c ? (float)(-sin(th)) : (float)cos(th));
        } else {
            int j = idx - 16384;
            int k = j & 63, w = j >> 6;
            int ky = k >> 1, c = k & 1;
            double th = 6.283185307179586476925286766559 * (double)((ky * w) & 255) / 256.0;
            BmC[j] = f2bf(c ? (float)(-sin(th)) : (float)cos(th));
        }
    } else {
        int idx = (b - 129) * BD + t;  // 0..2097151
        int o  = idx & 31;
        int i  = (idx >> 5) & 31;
        int ky = (idx >> 10) & 31;
        int m  = idx >> 15;
        float scale = (ky == 0 ? 1.0f : 2.0f) * (1.0f / 65536.0f);
        int widx = ((i * 32 + o) * 32 + (m & 31)) * 32 + ky;
        float wr, wi;
        if (m < 32) { wr = w1r[widx]; wi = w1i[widx]; }
        else        { wr = w2r[widx]; wi = w2i[widx]; }
        wpack[idx] = make_float2(wr * scale, wi * scale);
    }
}

// A1 (MFMA): Y[row][n] = sum_w x[row][w] * BmA[n][w].  M-tile=32 rows, N=64, K=256.
__global__ void k_dft_w_mfma(const float* __restrict__ x, const unsigned short* __restrict__ BmA,
                             float* __restrict__ Y) {
    __shared__ unsigned short As[32 * 264];   // 32 rows x 256 bf16, k-stride 264
    __shared__ unsigned short Bs[64 * 264];   // 64 n    x 256 bf16
    int t = threadIdx.x;
    {   // stage B (constant twiddle matrix): 64 shorts per thread = 8 uint4
        int n = t >> 2, c0 = (t & 3) * 64;
        const uint4* src = (const uint4*)(BmA + n * 256 + c0);
        unsigned short* dst = &Bs[n * 264 + c0];
#pragma unroll
        for (int j = 0; j < 8; ++j) *(uint4*)(dst + j * 8) = src[j];
    }
    {   // stage A: fp32 x -> bf16
        int r = t >> 3, c0 = (t & 7) * 32;
        const float4* src = (const float4*)(x + ((long)blockIdx.x * 32 + r) * 256 + c0);
        unsigned short* dst = &As[r * 264 + c0];
#pragma unroll
        for (int j = 0; j < 8; ++j) {
            float4 v = src[j];
            ushort4 bq;
            bq.x = f2bf(v.x); bq.y = f2bf(v.y); bq.z = f2bf(v.z); bq.w = f2bf(v.w);
            *(ushort4*)(dst + j * 4) = bq;
        }
    }
    __syncthreads();
    int wv = t >> 6, lane = t & 63;
    int m = lane & 15, quad = lane >> 4;
    int rows16 = (wv >> 1) * 16;
    int ntb = (wv & 1) * 2;
    f32x4 acc[2] = {};
#pragma unroll
    for (int kk = 0; kk < 8; ++kk) {
        bf16x8 af = *(const bf16x8*)&As[(rows16 + m) * 264 + kk * 32 + quad * 8];
#pragma unroll
        for (int j = 0; j < 2; ++j) {
            bf16x8 bf = *(const bf16x8*)&Bs[((ntb + j) * 16 + m) * 264 + kk * 32 + quad * 8];
            acc[j] = __builtin_amdgcn_mfma_f32_16x16x32_bf16(af, bf, acc[j], 0, 0, 0);
        }
    }
    long Mbase = (long)blockIdx.x * 32 + rows16;
#pragma unroll
    for (int j = 0; j < 2; ++j)
#pragma unroll
        for (int r = 0; r < 4; ++r)
            Y[(Mbase + quad * 4 + r) * 64 + (ntb + j) * 16 + m] = acc[j][r];
}

// A2: Z[bi][m][ky] = sum_h Y[bi][h][ky] * e^{-2pi i kx h/256}.  Rotation-recurrence twiddles.
// Grid 1024: block = bi*4+q handles ky slice [q*8, q*8+8). Thread: m = t&63, sub = t>>6 (2 ky each).
__global__ void k_dft_h(const float2* __restrict__ Y, const float2* __restrict__ tw,
                        float2* __restrict__ Z) {
    __shared__ __align__(16) float2 Ys[256][8];   // [h][kk] 16 KB
    int t = threadIdx.x;
    int bi = blockIdx.x >> 2, ky0 = (blockIdx.x & 3) * 8;
    const float2* Yb = Y + (long)bi * 8192 + ky0;
    for (int j = t; j < 2048; j += BD) Ys[j >> 3][j & 7] = Yb[(j >> 3) * 32 + (j & 7)];
    int m = t & 63, sub = t >> 6;
    int kx = (m < 32) ? m : m + 192;
    float2 st = tw[kx];                 // step e^{i 2pi kx/256}
    float C = st.x, S = st.y;
    float cr = 1.f, ci = 0.f;
    float zr0 = 0.f, zi0 = 0.f, zr1 = 0.f, zi1 = 0.f;
    __syncthreads();
    for (int h = 0; h < 256; ++h) {
        float4 y = *(const float4*)&Ys[h][sub * 2];   // wave-broadcast
        zr0 = fmaf(y.x, cr, fmaf(y.y,  ci, zr0));
        zi0 = fmaf(y.y, cr, fmaf(-y.x, ci, zi0));
        zr1 = fmaf(y.z, cr, fmaf(y.w,  ci, zr1));
        zi1 = fmaf(y.w, cr, fmaf(-y.z, ci, zi1));
        float nc = fmaf(cr, C, -ci * S);
        ci = fmaf(ci, C, cr * S);
        cr = nc;
    }
    float2* Zb = Z + ((long)bi * 64 + m) * 32 + ky0 + sub * 2;
    Zb[0] = make_float2(zr0, zi0);
    Zb[1] = make_float2(zr1, zi1);
}

// B: Zmix[b][o][m][ky] = sum_i Z[b][i][m][ky] * Wpack[m][ky][i][o]
__global__ void k_mix(const float2* __restrict__ Z, const float2* __restrict__ wpack,
                      float2* __restrict__ Zmix) {
    __shared__ float2 Zs[256];
    __shared__ float2 Ws[1024];
    int t = threadIdx.x;
    int mk = blockIdx.x;
    Zs[t] = Z[(long)t * 2048 + mk];
    for (int j = t; j < 1024; j += BD) Ws[j] = wpack[(long)mk * 1024 + j];
    __syncthreads();
    int b = t >> 5, o = t & 31;
    float ar = 0.f, ai = 0.f;
#pragma unroll
    for (int i = 0; i < 32; ++i) {
        float2 z = Zs[b * 32 + i];
        float2 w = Ws[i * 32 + o];
        ar = fmaf(z.x, w.x, fmaf(-z.y, w.y, ar));
        ai = fmaf(z.x, w.y, fmaf(z.y,  w.x, ai));
    }
    Zmix[(long)t * 2048 + mk] = make_float2(ar, ai);
}

// C1: G[bo][h][2ky+c] (bf16) = sum_m Zmix[bo][m][ky] * e^{+2pi i kx h/256}.
// Grid 1024: block = bo*4+q handles ky slice [q*8, q*8+8). Thread t = h.
__global__ void k_idft_h(const float2* __restrict__ Zmix, const float2* __restrict__ tw,
                         unsigned short* __restrict__ Gb) {
    __shared__ __align__(16) float2 Zs[64][8];    // [m][kk] 4 KB
    int t = threadIdx.x;
    int bo = blockIdx.x >> 2, ky0 = (blockIdx.x & 3) * 8;
    const float2* Zb = Zmix + (long)bo * 2048 + ky0;
    for (int j = t; j < 512; j += BD) Zs[j >> 3][j & 7] = Zb[(j >> 3) * 32 + (j & 7)];
    float2 st = tw[t];                  // step e^{i 2pi h/256}, h = t
    float C = st.x, S = st.y;
    __syncthreads();
    float gr[8], gi[8];
#pragma unroll
    for (int k = 0; k < 8; ++k) { gr[k] = 0.f; gi[k] = 0.f; }
    float cr = 1.f, ci = 0.f;
    for (int half = 0; half < 2; ++half) {
        if (half) { float2 s2 = tw[(224 * t) & 255]; cr = s2.x; ci = s2.y; }
        for (int mm = 0; mm < 32; ++mm) {
            int m = half * 32 + mm;
#pragma unroll
            for (int kk = 0; kk < 4; ++kk) {
                float4 z = *(const float4*)&Zs[m][kk * 2];   // wave-broadcast
                gr[kk*2]   = fmaf(z.x, cr, fmaf(-z.y, ci, gr[kk*2]));
                gi[kk*2]   = fmaf(z.y, cr, fmaf( z.x, ci, gi[kk*2]));
                gr[kk*2+1] = fmaf(z.z, cr, fmaf(-z.w, ci, gr[kk*2+1]));
                gi[kk*2+1] = fmaf(z.w, cr, fmaf( z.z, ci, gi[kk*2+1]));
            }
            float nc = fmaf(cr, C, -ci * S);
            ci = fmaf(ci, C, cr * S);
            cr = nc;
        }
    }
    unsigned* Gp = (unsigned*)(Gb + (((long)bo * 256 + t) * 64 + ky0 * 2));
#pragma unroll
    for (int k = 0; k < 8; ++k)
        Gp[k] = (unsigned)f2bf(gr[k]) | ((unsigned)f2bf(gi[k]) << 16);
}

// C2 (MFMA): out[row][w] = bias + sum_k G[row][k] * BmC[w][k].  M-tile=64, N=256, K=64.
__global__ void k_idft_w_mfma(const unsigned short* __restrict__ Gb,
                              const unsigned short* __restrict__ BmC,
                              const float* __restrict__ bias, float* __restrict__ out) {
    __shared__ unsigned short As[64 * 72];    // 64 rows x 64 bf16, k-stride 72
    __shared__ unsigned short Bs[256 * 72];   // 256 w   x 64 bf16
    int t = threadIdx.x;
    {   // stage B: 64 shorts per row = 8 uint4
        const uint4* src = (const uint4*)(BmC + t * 64);
        unsigned short* dst = &Bs[t * 72];
#pragma unroll
        for (int j = 0; j < 8; ++j) *(uint4*)(dst + j * 8) = src[j];
    }
    {   // stage A
        int r = t >> 2, c0 = (t & 3) * 16;
        const uint4* src = (const uint4*)(Gb + ((long)blockIdx.x * 64 + r) * 64 + c0);
        unsigned short* dst = &As[r * 72 + c0];
        *(uint4*)(dst) = src[0];
        *(uint4*)(dst + 8) = src[1];
    }
    __syncthreads();
    int wv = t >> 6, lane = t & 63;
    int m = lane & 15, quad = lane >> 4;
    f32x4 acc[16] = {};
    bf16x8 a0 = *(const bf16x8*)&As[(wv * 16 + m) * 72 + quad * 8];
    bf16x8 a1 = *(const bf16x8*)&As[(wv * 16 + m) * 72 + 32 + quad * 8];
#pragma unroll
    for (int nt = 0; nt < 16; ++nt) {
        bf16x8 b0 = *(const bf16x8*)&Bs[(nt * 16 + m) * 72 + quad * 8];
        bf16x8 b1 = *(const bf16x8*)&Bs[(nt * 16 + m) * 72 + 32 + quad * 8];
        acc[nt] = __builtin_amdgcn_mfma_f32_16x16x32_bf16(a0, b0, acc[nt], 0, 0, 0);
        acc[nt] = __builtin_amdgcn_mfma_f32_16x16x32_bf16(a1, b1, acc[nt], 0, 0, 0);
    }
    float bv = bias[(blockIdx.x >> 2) & 31];
    long rowbase = (long)blockIdx.x * 64 + wv * 16;
#pragma unroll
    for (int nt = 0; nt < 16; ++nt)
#pragma unroll
        for (int r = 0; r < 4; ++r)
            out[(rowbase + quad * 4 + r) * 256 + nt * 16 + m] = acc[nt][r] + bv;
}

extern "C" void kernel_launch(void* const* d_in, const int* in_sizes, int n_in,
                              void* d_out, int out_size, void* d_ws, size_t ws_size,
                              hipStream_t stream) {
    const float* x    = (const float*)d_in[0];
    const float* w1r  = (const float*)d_in[1];
    const float* w1i  = (const float*)d_in[2];
    const float* w2r  = (const float*)d_in[3];
    const float* w2i  = (const float*)d_in[4];
    const float* bias = (const float*)d_in[5];

    char* ws = (char*)d_ws;
    float2* tw             = (float2*)(ws);                                  // 2 KB (slot 4KB)
    float2* wpack          = (float2*)(ws + 4096);                           // 16 MB
    unsigned short* BmA    = (unsigned short*)(ws + 4096 + (16l << 20));     // 32 KB
    unsigned short* BmC    = BmA + 64 * 256;                                 // 32 KB
    float* Y               = (float*)(ws + 4096 + (16l << 20) + 65536);      // 16 MB
    float2* Z              = (float2*)((char*)Y + (16l << 20));              // 4 MB
    float2* Zmix           = (float2*)((char*)Z + (4l << 20));               // 4 MB
    unsigned short* Gb     = (unsigned short*)Y;   // alias: Y dead after k_dft_h
    float* out             = (float*)d_out;

    k_setup       <<<1 + 128 + 8192, BD, 0, stream>>>(tw, BmA, BmC, w1r, w1i, w2r, w2i, wpack);
    k_dft_w_mfma  <<<2048, BD, 0, stream>>>(x, BmA, Y);
    k_dft_h       <<<1024, BD, 0, stream>>>((const float2*)Y, tw, Z);
    k_mix         <<<2048, BD, 0, stream>>>(Z, wpack, Zmix);
    k_idft_h      <<<1024, BD, 0, stream>>>(Zmix, tw, Gb);
    k_idft_w_mfma <<<1024, BD, 0, stream>>>(Gb, BmC, bias, out);
}

// Round 2
// 214.989 us; speedup vs baseline: 1.0807x; 1.0807x over previous
//
#include <hip/hip_runtime.h>
#include <hip/hip_bf16.h>

// SpectralConv2d (FNO): B=8, C_IN=C_OUT=32, H=W=256, modes 32x32 (low kx) + 32x32 (high kx), ky 0..31.
// Pipeline: rFFT(w) as bf16-MFMA GEMM -> FFT(h) fp32 w/ rotation-recurrence twiddles (ky-split x4)
//           -> complex mix -> iFFT(h) fp32 recurrence (ky-split x4, writes bf16)
//           -> irFFT(w)+bias as bf16-MFMA GEMM.
// R1: coalesced wpack transpose (was 16x-amplified gather), mk-grouped k_mix (was 8x-amplified
//     gather+scatter), LDS-restaged coalesced Z write in k_dft_h (was 4x-amplified scatter).

#define BD 256

typedef __attribute__((ext_vector_type(8))) short bf16x8;
typedef __attribute__((ext_vector_type(4))) float f32x4;

__device__ inline unsigned short f2bf(float f) {
    union { float f; unsigned u; } v; v.f = f;
    unsigned r = v.u + 0x7FFF + ((v.u >> 16) & 1);   // RNE
    return (unsigned short)(r >> 16);
}

// Merged setup:
//   block 0        -> twiddle table tw[t] = (cos, sin)(2pi t/256)
//   blocks 1..128  -> BmA [64][256], BmC [256][64] bf16 DFT matrices
//   blocks 129..640-> wpack transpose: wpack[(m*32+ky)*1024 + io] = w[io][m'*32+ky] * scale
//                     (pure 1024x1024 transpose per half, LDS-tiled 64x64, coalesced both sides)
__global__ void k_setup(float2* __restrict__ tw,
                        unsigned short* __restrict__ BmA, unsigned short* __restrict__ BmC,
                        const float* __restrict__ w1r, const float* __restrict__ w1i,
                        const float* __restrict__ w2r, const float* __restrict__ w2i,
                        float2* __restrict__ wpack) {
    __shared__ float Tr[64][65];
    __shared__ float Ti[64][65];
    int b = blockIdx.x, t = threadIdx.x;
    if (b == 0) {
        double th = 6.283185307179586476925286766559 * (double)t / 256.0;
        tw[t] = make_float2((float)cos(th), (float)sin(th));
    } else if (b <= 128) {
        int idx = (b - 1) * BD + t;    // 0..32767
        if (idx < 16384) {
            int w = idx & 255, n = idx >> 8;
            int ky = n >> 1, c = n & 1;
            double th = 6.283185307179586476925286766559 * (double)((ky * w) & 255) / 256.0;
            BmA[idx] = f2bf(c ? (float)(-sin(th)) : (float)cos(th));
        } else {
            int j = idx - 16384;
            int k = j & 63, w = j >> 6;
            int ky = k >> 1, c = k & 1;
            double th = 6.283185307179586476925286766559 * (double)((ky * w) & 255) / 256.0;
            BmC[j] = f2bf(c ? (float)(-sin(th)) : (float)cos(th));
        }
    } else {
        int blk = b - 129;              // 0..511
        int half = blk >> 8;            // 0: w1 (m<32), 1: w2 (m>=32)
        int tile = blk & 255;
        int tr = tile >> 4, tc = tile & 15;     // io-tile, cm-tile
        int io0 = tr * 64, cm0 = tc * 64;
        const float* wr = half ? w2r : w1r;
        const float* wi = half ? w2i : w1i;
        int rr = t >> 2, c0 = (t & 3) * 16;
        {   // load 64x64 tile, coalesced: each thread 4 float4 per array
            const float4* srcr = (const float4*)(wr + (long)(io0 + rr) * 1024 + cm0 + c0);
            const float4* srci = (const float4*)(wi + (long)(io0 + rr) * 1024 + cm0 + c0);
#pragma unroll
            for (int p = 0; p < 4; ++p) {
                float4 vr = srcr[p], vi = srci[p];
                int cc = c0 + p * 4;
                Tr[rr][cc + 0] = vr.x; Tr[rr][cc + 1] = vr.y; Tr[rr][cc + 2] = vr.z; Tr[rr][cc + 3] = vr.w;
                Ti[rr][cc + 0] = vi.x; Ti[rr][cc + 1] = vi.y; Ti[rr][cc + 2] = vi.z; Ti[rr][cc + 3] = vi.w;
            }
        }
        __syncthreads();
        {   // write transposed, coalesced: out row = cm, cols = io
            int cm = cm0 + rr;
            int ky = cm & 31;
            float s = (ky == 0 ? 1.0f : 2.0f) * (1.0f / 65536.0f);
            float2* dst = wpack + ((long)(half * 1024 + cm)) * 1024 + io0 + c0;
#pragma unroll
            for (int k = 0; k < 16; ++k)
                dst[k] = make_float2(Tr[c0 + k][rr] * s, Ti[c0 + k][rr] * s);
        }
    }
}

// A1 (MFMA): Y[row][n] = sum_w x[row][w] * BmA[n][w].  M-tile=32 rows, N=64, K=256.
__global__ void k_dft_w_mfma(const float* __restrict__ x, const unsigned short* __restrict__ BmA,
                             float* __restrict__ Y) {
    __shared__ unsigned short As[32 * 264];   // 32 rows x 256 bf16, k-stride 264
    __shared__ unsigned short Bs[64 * 264];   // 64 n    x 256 bf16
    int t = threadIdx.x;
    {   // stage B (constant twiddle matrix): 64 shorts per thread = 8 uint4
        int n = t >> 2, c0 = (t & 3) * 64;
        const uint4* src = (const uint4*)(BmA + n * 256 + c0);
        unsigned short* dst = &Bs[n * 264 + c0];
#pragma unroll
        for (int j = 0; j < 8; ++j) *(uint4*)(dst + j * 8) = src[j];
    }
    {   // stage A: fp32 x -> bf16
        int r = t >> 3, c0 = (t & 7) * 32;
        const float4* src = (const float4*)(x + ((long)blockIdx.x * 32 + r) * 256 + c0);
        unsigned short* dst = &As[r * 264 + c0];
#pragma unroll
        for (int j = 0; j < 8; ++j) {
            float4 v = src[j];
            ushort4 bq;
            bq.x = f2bf(v.x); bq.y = f2bf(v.y); bq.z = f2bf(v.z); bq.w = f2bf(v.w);
            *(ushort4*)(dst + j * 4) = bq;
        }
    }
    __syncthreads();
    int wv = t >> 6, lane = t & 63;
    int m = lane & 15, quad = lane >> 4;
    int rows16 = (wv >> 1) * 16;
    int ntb = (wv & 1) * 2;
    f32x4 acc[2] = {};
#pragma unroll
    for (int kk = 0; kk < 8; ++kk) {
        bf16x8 af = *(const bf16x8*)&As[(rows16 + m) * 264 + kk * 32 + quad * 8];
#pragma unroll
        for (int j = 0; j < 2; ++j) {
            bf16x8 bf = *(const bf16x8*)&Bs[((ntb + j) * 16 + m) * 264 + kk * 32 + quad * 8];
            acc[j] = __builtin_amdgcn_mfma_f32_16x16x32_bf16(af, bf, acc[j], 0, 0, 0);
        }
    }
    long Mbase = (long)blockIdx.x * 32 + rows16;
#pragma unroll
    for (int j = 0; j < 2; ++j)
#pragma unroll
        for (int r = 0; r < 4; ++r)
            Y[(Mbase + quad * 4 + r) * 64 + (ntb + j) * 16 + m] = acc[j][r];
}

// A2: Z[bi][m][ky] = sum_h Y[bi][h][ky] * e^{-2pi i kx h/256}.  Rotation-recurrence twiddles.
// Grid 1024: block = bi*4+q handles ky slice [q*8, q*8+8). Thread: m = t&63, sub = t>>6 (2 ky each).
// R1: output restaged through LDS (reusing Ys) -> coalesced 64B-per-row writes.
__global__ void k_dft_h(const float2* __restrict__ Y, const float2* __restrict__ tw,
                        float2* __restrict__ Z) {
    __shared__ __align__(16) float2 Ys[256][8];   // [h][kk] 16 KB
    int t = threadIdx.x;
    int bi = blockIdx.x >> 2, ky0 = (blockIdx.x & 3) * 8;
    const float2* Yb = Y + (long)bi * 8192 + ky0;
    for (int j = t; j < 2048; j += BD) Ys[j >> 3][j & 7] = Yb[(j >> 3) * 32 + (j & 7)];
    int m = t & 63, sub = t >> 6;
    int kx = (m < 32) ? m : m + 192;
    float2 st = tw[kx];                 // step e^{i 2pi kx/256}
    float C = st.x, S = st.y;
    float cr = 1.f, ci = 0.f;
    float zr0 = 0.f, zi0 = 0.f, zr1 = 0.f, zi1 = 0.f;
    __syncthreads();
    for (int h = 0; h < 256; ++h) {
        float4 y = *(const float4*)&Ys[h][sub * 2];   // wave-broadcast
        zr0 = fmaf(y.x, cr, fmaf(y.y,  ci, zr0));
        zi0 = fmaf(y.y, cr, fmaf(-y.x, ci, zi0));
        zr1 = fmaf(y.z, cr, fmaf(y.w,  ci, zr1));
        zi1 = fmaf(y.w, cr, fmaf(-y.z, ci, zi1));
        float nc = fmaf(cr, C, -ci * S);
        ci = fmaf(ci, C, cr * S);
        cr = nc;
    }
    __syncthreads();                    // all reads of Ys done; reuse as staging
    float2* Zsh = &Ys[0][0];            // [64 m][8 ky] = 512 float2
    Zsh[m * 8 + sub * 2 + 0] = make_float2(zr0, zi0);
    Zsh[m * 8 + sub * 2 + 1] = make_float2(zr1, zi1);
    __syncthreads();
    {   // cooperative coalesced write: 64B chunk per m-row
        int mm = t >> 2, p = t & 3;     // 256 threads = 64 m x 4 float4
        *(float4*)&Z[(long)bi * 2048 + mm * 32 + ky0 + p * 2] = *(float4*)&Zsh[mm * 8 + p * 2];
    }
}

// B: Zmix[b][o][m][ky] = sum_i Z[b][i][m][ky] * Wpack[m][ky][i][o]
// R1: block = 4 consecutive mk (same m). Ws staged as one contiguous 32KB read; Zs staged in
//     32B row-chunks; output restaged through LDS and written in 32B row-chunks.
__global__ void k_mix(const float2* __restrict__ Z, const float2* __restrict__ wpack,
                      float2* __restrict__ Zmix) {
    __shared__ float2 Ws[4][1024];   // 32 KB
    __shared__ float2 Zs[256][4];    // 8 KB  [bi][kk]
    __shared__ float2 Os[256][4];    // 8 KB  [bo][kk]
    int t = threadIdx.x;
    int mk0 = blockIdx.x * 4;
    {   // stage W: contiguous, fully coalesced
        const float4* src = (const float4*)(wpack + (long)mk0 * 1024);
        float4* dst = (float4*)&Ws[0][0];
        for (int j = t; j < 2048; j += BD) dst[j] = src[j];
    }
    for (int j = t; j < 512; j += BD) {   // stage Z: 32B per bi-row
        int bi = j >> 1, p = j & 1;
        *(float4*)&Zs[bi][p * 2] = *(const float4*)&Z[(long)bi * 2048 + mk0 + p * 2];
    }
    __syncthreads();
    int o = t & 31, kk = (t >> 5) & 3, bh = t >> 7;
    float ar[4], ai[4];
#pragma unroll
    for (int j = 0; j < 4; ++j) { ar[j] = 0.f; ai[j] = 0.f; }
    for (int i = 0; i < 32; ++i) {
        float2 w = Ws[kk][i * 32 + o];
#pragma unroll
        for (int j = 0; j < 4; ++j) {
            float2 z = Zs[(bh * 4 + j) * 32 + i][kk];   // wave-broadcast
            ar[j] = fmaf(z.x, w.x, fmaf(-z.y, w.y, ar[j]));
            ai[j] = fmaf(z.x, w.y, fmaf( z.y, w.x, ai[j]));
        }
    }
#pragma unroll
    for (int j = 0; j < 4; ++j)
        Os[(bh * 4 + j) * 32 + o][kk] = make_float2(ar[j], ai[j]);
    __syncthreads();
    for (int j = t; j < 512; j += BD) {   // coalesced write-out: 32B per bo-row
        int row = j >> 1, p = j & 1;
        *(float4*)&Zmix[(long)row * 2048 + mk0 + p * 2] = *(float4*)&Os[row][p * 2];
    }
}

// C1: G[bo][h][2ky+c] (bf16) = sum_m Zmix[bo][m][ky] * e^{+2pi i kx h/256}.
// Grid 1024: block = bo*4+q handles ky slice [q*8, q*8+8). Thread t = h.
__global__ void k_idft_h(const float2* __restrict__ Zmix, const float2* __restrict__ tw,
                         unsigned short* __restrict__ Gb) {
    __shared__ __align__(16) float2 Zs[64][8];    // [m][kk] 4 KB
    int t = threadIdx.x;
    int bo = blockIdx.x >> 2, ky0 = (blockIdx.x & 3) * 8;
    const float2* Zb = Zmix + (long)bo * 2048 + ky0;
    for (int j = t; j < 512; j += BD) Zs[j >> 3][j & 7] = Zb[(j >> 3) * 32 + (j & 7)];
    float2 st = tw[t];                  // step e^{i 2pi h/256}, h = t
    float C = st.x, S = st.y;
    __syncthreads();
    float gr[8], gi[8];
#pragma unroll
    for (int k = 0; k < 8; ++k) { gr[k] = 0.f; gi[k] = 0.f; }
    float cr = 1.f, ci = 0.f;
    for (int half = 0; half < 2; ++half) {
        if (half) { float2 s2 = tw[(224 * t) & 255]; cr = s2.x; ci = s2.y; }
        for (int mm = 0; mm < 32; ++mm) {
            int m = half * 32 + mm;
#pragma unroll
            for (int kk = 0; kk < 4; ++kk) {
                float4 z = *(const float4*)&Zs[m][kk * 2];   // wave-broadcast
                gr[kk*2]   = fmaf(z.x, cr, fmaf(-z.y, ci, gr[kk*2]));
                gi[kk*2]   = fmaf(z.y, cr, fmaf( z.x, ci, gi[kk*2]));
                gr[kk*2+1] = fmaf(z.z, cr, fmaf(-z.w, ci, gr[kk*2+1]));
                gi[kk*2+1] = fmaf(z.w, cr, fmaf( z.z, ci, gi[kk*2+1]));
            }
            float nc = fmaf(cr, C, -ci * S);
            ci = fmaf(ci, C, cr * S);
            cr = nc;
        }
    }
    unsigned* Gp = (unsigned*)(Gb + (((long)bo * 256 + t) * 64 + ky0 * 2));
#pragma unroll
    for (int k = 0; k < 8; ++k)
        Gp[k] = (unsigned)f2bf(gr[k]) | ((unsigned)f2bf(gi[k]) << 16);
}

// C2 (MFMA): out[row][w] = bias + sum_k G[row][k] * BmC[w][k].  M-tile=64, N=256, K=64.
__global__ void k_idft_w_mfma(const unsigned short* __restrict__ Gb,
                              const unsigned short* __restrict__ BmC,
                              const float* __restrict__ bias, float* __restrict__ out) {
    __shared__ unsigned short As[64 * 72];    // 64 rows x 64 bf16, k-stride 72
    __shared__ unsigned short Bs[256 * 72];   // 256 w   x 64 bf16
    int t = threadIdx.x;
    {   // stage B: 64 shorts per row = 8 uint4
        const uint4* src = (const uint4*)(BmC + t * 64);
        unsigned short* dst = &Bs[t * 72];
#pragma unroll
        for (int j = 0; j < 8; ++j) *(uint4*)(dst + j * 8) = src[j];
    }
    {   // stage A
        int r = t >> 2, c0 = (t & 3) * 16;
        const uint4* src = (const uint4*)(Gb + ((long)blockIdx.x * 64 + r) * 64 + c0);
        unsigned short* dst = &As[r * 72 + c0];
        *(uint4*)(dst) = src[0];
        *(uint4*)(dst + 8) = src[1];
    }
    __syncthreads();
    int wv = t >> 6, lane = t & 63;
    int m = lane & 15, quad = lane >> 4;
    f32x4 acc[16] = {};
    bf16x8 a0 = *(const bf16x8*)&As[(wv * 16 + m) * 72 + quad * 8];
    bf16x8 a1 = *(const bf16x8*)&As[(wv * 16 + m) * 72 + 32 + quad * 8];
#pragma unroll
    for (int nt = 0; nt < 16; ++nt) {
        bf16x8 b0 = *(const bf16x8*)&Bs[(nt * 16 + m) * 72 + quad * 8];
        bf16x8 b1 = *(const bf16x8*)&Bs[(nt * 16 + m) * 72 + 32 + quad * 8];
        acc[nt] = __builtin_amdgcn_mfma_f32_16x16x32_bf16(a0, b0, acc[nt], 0, 0, 0);
        acc[nt] = __builtin_amdgcn_mfma_f32_16x16x32_bf16(a1, b1, acc[nt], 0, 0, 0);
    }
    float bv = bias[(blockIdx.x >> 2) & 31];
    long rowbase = (long)blockIdx.x * 64 + wv * 16;
#pragma unroll
    for (int nt = 0; nt < 16; ++nt)
#pragma unroll
        for (int r = 0; r < 4; ++r)
            out[(rowbase + quad * 4 + r) * 256 + nt * 16 + m] = acc[nt][r] + bv;
}

extern "C" void kernel_launch(void* const* d_in, const int* in_sizes, int n_in,
                              void* d_out, int out_size, void* d_ws, size_t ws_size,
                              hipStream_t stream) {
    const float* x    = (const float*)d_in[0];
    const float* w1r  = (const float*)d_in[1];
    const float* w1i  = (const float*)d_in[2];
    const float* w2r  = (const float*)d_in[3];
    const float* w2i  = (const float*)d_in[4];
    const float* bias = (const float*)d_in[5];

    char* ws = (char*)d_ws;
    float2* tw             = (float2*)(ws);                                  // 2 KB (slot 4KB)
    float2* wpack          = (float2*)(ws + 4096);                           // 16 MB
    unsigned short* BmA    = (unsigned short*)(ws + 4096 + (16l << 20));     // 32 KB
    unsigned short* BmC    = BmA + 64 * 256;                                 // 32 KB
    float* Y               = (float*)(ws + 4096 + (16l << 20) + 65536);      // 16 MB
    float2* Z              = (float2*)((char*)Y + (16l << 20));              // 4 MB
    float2* Zmix           = (float2*)((char*)Z + (4l << 20));               // 4 MB
    unsigned short* Gb     = (unsigned short*)Y;   // alias: Y dead after k_dft_h
    float* out             = (float*)d_out;

    k_setup       <<<1 + 128 + 512, BD, 0, stream>>>(tw, BmA, BmC, w1r, w1i, w2r, w2i, wpack);
    k_dft_w_mfma  <<<2048, BD, 0, stream>>>(x, BmA, Y);
    k_dft_h       <<<1024, BD, 0, stream>>>((const float2*)Y, tw, Z);
    k_mix         <<<512, BD, 0, stream>>>(Z, wpack, Zmix);
    k_idft_h      <<<1024, BD, 0, stream>>>(Zmix, tw, Gb);
    k_idft_w_mfma <<<1024, BD, 0, stream>>>(Gb, BmC, bias, out);
}

// Round 3
// 190.552 us; speedup vs baseline: 1.2193x; 1.1282x over previous
//
#include <hip/hip_runtime.h>
#include <hip/hip_bf16.h>

// SpectralConv2d (FNO): B=8, C_IN=C_OUT=32, H=W=256, modes 32x32 (low kx) + 32x32 (high kx), ky 0..31.
// R2: fused pipeline (4 kernels):
//   k_setup: twiddles + bf16 DFT matrices + wpack transpose
//   k_fftA : rFFT(w) bf16-MFMA GEMM (h-chunked, Y in LDS) + FFT(h) fp32 recurrence -> Z
//   k_mix  : complex channel mixing
//   k_fftC : iFFT(h) fp32 recurrence (G in LDS) + irFFT(w)+bias bf16-MFMA GEMM -> out
// Y and G intermediates never touch HBM (were 48 MB of traffic); x-prefetch overlaps h-DFT VALU.

#define BD 256

typedef __attribute__((ext_vector_type(8))) short bf16x8;
typedef __attribute__((ext_vector_type(4))) float f32x4;

__device__ inline unsigned short f2bf(float f) {
    union { float f; unsigned u; } v; v.f = f;
    unsigned r = v.u + 0x7FFF + ((v.u >> 16) & 1);   // RNE
    return (unsigned short)(r >> 16);
}

// Merged setup:
//   block 0        -> twiddle table tw[t] = (cos, sin)(2pi t/256)
//   blocks 1..128  -> BmA [64][256], BmC [256][64] bf16 DFT matrices
//   blocks 129..640-> wpack transpose: wpack[(m*32+ky)*1024 + io] = w[io][m'*32+ky] * scale
__global__ void k_setup(float2* __restrict__ tw,
                        unsigned short* __restrict__ BmA, unsigned short* __restrict__ BmC,
                        const float* __restrict__ w1r, const float* __restrict__ w1i,
                        const float* __restrict__ w2r, const float* __restrict__ w2i,
                        float2* __restrict__ wpack) {
    __shared__ float Tr[64][65];
    __shared__ float Ti[64][65];
    int b = blockIdx.x, t = threadIdx.x;
    if (b == 0) {
        double th = 6.283185307179586476925286766559 * (double)t / 256.0;
        tw[t] = make_float2((float)cos(th), (float)sin(th));
    } else if (b <= 128) {
        int idx = (b - 1) * BD + t;    // 0..32767
        if (idx < 16384) {
            int w = idx & 255, n = idx >> 8;
            int ky = n >> 1, c = n & 1;
            double th = 6.283185307179586476925286766559 * (double)((ky * w) & 255) / 256.0;
            BmA[idx] = f2bf(c ? (float)(-sin(th)) : (float)cos(th));
        } else {
            int j = idx - 16384;
            int k = j & 63, w = j >> 6;
            int ky = k >> 1, c = k & 1;
            double th = 6.283185307179586476925286766559 * (double)((ky * w) & 255) / 256.0;
            BmC[j] = f2bf(c ? (float)(-sin(th)) : (float)cos(th));
        }
    } else {
        int blk = b - 129;              // 0..511
        int half = blk >> 8;            // 0: w1 (m<32), 1: w2 (m>=32)
        int tile = blk & 255;
        int tr = tile >> 4, tc = tile & 15;     // io-tile, cm-tile
        int io0 = tr * 64, cm0 = tc * 64;
        const float* wr = half ? w2r : w1r;
        const float* wi = half ? w2i : w1i;
        int rr = t >> 2, c0 = (t & 3) * 16;
        {   // load 64x64 tile, coalesced
            const float4* srcr = (const float4*)(wr + (long)(io0 + rr) * 1024 + cm0 + c0);
            const float4* srci = (const float4*)(wi + (long)(io0 + rr) * 1024 + cm0 + c0);
#pragma unroll
            for (int p = 0; p < 4; ++p) {
                float4 vr = srcr[p], vi = srci[p];
                int cc = c0 + p * 4;
                Tr[rr][cc + 0] = vr.x; Tr[rr][cc + 1] = vr.y; Tr[rr][cc + 2] = vr.z; Tr[rr][cc + 3] = vr.w;
                Ti[rr][cc + 0] = vi.x; Ti[rr][cc + 1] = vi.y; Ti[rr][cc + 2] = vi.z; Ti[rr][cc + 3] = vi.w;
            }
        }
        __syncthreads();
        {   // write transposed, coalesced
            int cm = cm0 + rr;
            int ky = cm & 31;
            float s = (ky == 0 ? 1.0f : 2.0f) * (1.0f / 65536.0f);
            float2* dst = wpack + ((long)(half * 1024 + cm)) * 1024 + io0 + c0;
#pragma unroll
            for (int k = 0; k < 16; ++k)
                dst[k] = make_float2(Tr[c0 + k][rr] * s, Ti[c0 + k][rr] * s);
        }
    }
}

// Fused A: per block bi (b*32+c_in): 8 h-chunks of 32 rows:
//   W-DFT MFMA (M=32,N=64,K=256) -> Ys LDS; then fp32 h-DFT accumulate over the 32 h.
// Thread roles: MFMA wave tile (mh=wv&1, nq=wv>>1); h-DFT (kx = t&63, ky-group g = t>>6, 4 ky).
__global__ __launch_bounds__(512) void k_fftA(const float* __restrict__ x,
                                              const unsigned short* __restrict__ BmA,
                                              const float2* __restrict__ tw,
                                              float2* __restrict__ Z) {
    __shared__ __align__(16) unsigned short Bs[64 * 264];   // 33792 B (persistent twiddles)
    __shared__ __align__(16) unsigned short As[32 * 264];   // 16896 B (chunk staging; Z out reuse)
    __shared__ __align__(16) float Ys[32 * 64];             //  8192 B (chunk W-DFT output)
    int t = threadIdx.x, bi = blockIdx.x;
    {   // stage Bs once: n = t>>3, c0 = (t&7)*32
        int n = t >> 3, c0 = (t & 7) * 32;
        const uint4* src = (const uint4*)(BmA + n * 256 + c0);
        unsigned short* dst = &Bs[n * 264 + c0];
#pragma unroll
        for (int j = 0; j < 4; ++j) *(uint4*)(dst + j * 8) = src[j];
    }
    // x staging geometry: 32 rows x 256 cols per chunk; thread r = t>>4, c0 = (t&15)*16
    int sr = t >> 4, sc = (t & 15) * 16;
    const float* xrow = x + ((long)bi * 256 + sr) * 256 + sc;
    float4 xb[4];
#pragma unroll
    for (int j = 0; j < 4; ++j) xb[j] = *(const float4*)(xrow + j * 4);
    {   // write As chunk 0
        unsigned short* dst = &As[sr * 264 + sc];
#pragma unroll
        for (int j = 0; j < 4; ++j) {
            float4 v = xb[j]; ushort4 bq;
            bq.x = f2bf(v.x); bq.y = f2bf(v.y); bq.z = f2bf(v.z); bq.w = f2bf(v.w);
            *(ushort4*)(dst + j * 4) = bq;
        }
    }
    __syncthreads();
    int wv = t >> 6, lane = t & 63, lm = lane & 15, quad = lane >> 4;
    int mh = wv & 1, nq = wv >> 1;
    int kxi = t & 63, g = wv;
    int kxv = (kxi < 32) ? kxi : kxi + 192;
    float2 st = tw[kxv];
    float C = st.x, S = st.y;
    float zr[4] = {0.f, 0.f, 0.f, 0.f}, zi[4] = {0.f, 0.f, 0.f, 0.f};
    for (int c = 0; c < 8; ++c) {
        // MFMA: Ys[row][n] = sum_w As[row][w] * Bs[n][w]
        f32x4 acc = {};
#pragma unroll
        for (int kk = 0; kk < 8; ++kk) {
            bf16x8 af = *(const bf16x8*)&As[(mh * 16 + lm) * 264 + kk * 32 + quad * 8];
            bf16x8 bf = *(const bf16x8*)&Bs[(nq * 16 + lm) * 264 + kk * 32 + quad * 8];
            acc = __builtin_amdgcn_mfma_f32_16x16x32_bf16(af, bf, acc, 0, 0, 0);
        }
        if (c < 7) {   // issue next chunk's x loads (in flight across the h-DFT)
            const float* xr = xrow + (c + 1) * 32 * 256;
#pragma unroll
            for (int j = 0; j < 4; ++j) xb[j] = *(const float4*)(xr + j * 4);
        }
#pragma unroll
        for (int r = 0; r < 4; ++r)
            Ys[(mh * 16 + quad * 4 + r) * 64 + nq * 16 + lm] = acc[r];
        __syncthreads();
        // h-DFT accumulate over this chunk's 32 h (exact table restart per chunk)
        float2 cw = tw[(kxv * (c * 32)) & 255];
        float cr = cw.x, ci = cw.y;
        for (int hh = 0; hh < 32; ++hh) {
            float4 y0 = *(const float4*)&Ys[hh * 64 + g * 8];       // wave-broadcast
            float4 y1 = *(const float4*)&Ys[hh * 64 + g * 8 + 4];
            zr[0] = fmaf(y0.x, cr, fmaf(y0.y,  ci, zr[0]));
            zi[0] = fmaf(y0.y, cr, fmaf(-y0.x, ci, zi[0]));
            zr[1] = fmaf(y0.z, cr, fmaf(y0.w,  ci, zr[1]));
            zi[1] = fmaf(y0.w, cr, fmaf(-y0.z, ci, zi[1]));
            zr[2] = fmaf(y1.x, cr, fmaf(y1.y,  ci, zr[2]));
            zi[2] = fmaf(y1.y, cr, fmaf(-y1.x, ci, zi[2]));
            zr[3] = fmaf(y1.z, cr, fmaf(y1.w,  ci, zr[3]));
            zi[3] = fmaf(y1.w, cr, fmaf(-y1.z, ci, zi[3]));
            float nc = fmaf(cr, C, -ci * S);
            ci = fmaf(ci, C, cr * S);
            cr = nc;
        }
        if (c < 7) {   // write As for chunk c+1
            unsigned short* dst = &As[sr * 264 + sc];
#pragma unroll
            for (int j = 0; j < 4; ++j) {
                float4 v = xb[j]; ushort4 bq;
                bq.x = f2bf(v.x); bq.y = f2bf(v.y); bq.z = f2bf(v.z); bq.w = f2bf(v.w);
                *(ushort4*)(dst + j * 4) = bq;
            }
        }
        __syncthreads();
    }
    // Z epilogue: restage through LDS (reuse As) -> coalesced write
    float2* Zo = (float2*)As;
    {
#pragma unroll
        for (int j = 0; j < 4; ++j)
            Zo[kxi * 32 + g * 4 + j] = make_float2(zr[j], zi[j]);
    }
    __syncthreads();
    {
        float4* dst = (float4*)(Z + (long)bi * 2048);
        const float4* src = (const float4*)Zo;
        dst[t] = src[t];
        dst[t + 512] = src[t + 512];
    }
}

// B: Zmix[b][o][m][ky] = sum_i Z[b][i][m][ky] * Wpack[m][ky][i][o]  (unchanged from R1)
__global__ void k_mix(const float2* __restrict__ Z, const float2* __restrict__ wpack,
                      float2* __restrict__ Zmix) {
    __shared__ float2 Ws[4][1024];   // 32 KB
    __shared__ float2 Zs[256][4];    // 8 KB  [bi][kk]
    __shared__ float2 Os[256][4];    // 8 KB  [bo][kk]
    int t = threadIdx.x;
    int mk0 = blockIdx.x * 4;
    {
        const float4* src = (const float4*)(wpack + (long)mk0 * 1024);
        float4* dst = (float4*)&Ws[0][0];
        for (int j = t; j < 2048; j += BD) dst[j] = src[j];
    }
    for (int j = t; j < 512; j += BD) {
        int bi = j >> 1, p = j & 1;
        *(float4*)&Zs[bi][p * 2] = *(const float4*)&Z[(long)bi * 2048 + mk0 + p * 2];
    }
    __syncthreads();
    int o = t & 31, kk = (t >> 5) & 3, bh = t >> 7;
    float ar[4], ai[4];
#pragma unroll
    for (int j = 0; j < 4; ++j) { ar[j] = 0.f; ai[j] = 0.f; }
    for (int i = 0; i < 32; ++i) {
        float2 w = Ws[kk][i * 32 + o];
#pragma unroll
        for (int j = 0; j < 4; ++j) {
            float2 z = Zs[(bh * 4 + j) * 32 + i][kk];   // wave-broadcast
            ar[j] = fmaf(z.x, w.x, fmaf(-z.y, w.y, ar[j]));
            ai[j] = fmaf(z.x, w.y, fmaf( z.y, w.x, ai[j]));
        }
    }
#pragma unroll
    for (int j = 0; j < 4; ++j)
        Os[(bh * 4 + j) * 32 + o][kk] = make_float2(ar[j], ai[j]);
    __syncthreads();
    for (int j = t; j < 512; j += BD) {
        int row = j >> 1, p = j & 1;
        *(float4*)&Zmix[(long)row * 2048 + mk0 + p * 2] = *(float4*)&Os[row][p * 2];
    }
}

// Fused C: block = (bo, h-half). C1: iFFT(h) fp32 recurrence -> G rows (bf16) in LDS.
// C2: MFMA out[128 h][256 w] = G * BmC^T + bias, BmC staged in 2 halves over the dead Zs buffer.
__global__ __launch_bounds__(256) void k_fftC(const float2* __restrict__ Zmix,
                                              const float2* __restrict__ tw,
                                              const unsigned short* __restrict__ BmC,
                                              const float* __restrict__ bias,
                                              float* __restrict__ out) {
    __shared__ __align__(16) unsigned short Gs[128 * 72];   // 18432 B
    __shared__ __align__(16) char buf[128 * 72 * 2];        // 18432 B: Zs then Bs-half overlay
    int t = threadIdx.x;
    int bo = blockIdx.x >> 1, hb = blockIdx.x & 1;
    float2* Zs = (float2*)buf;                  // [64 m][32 ky]
    unsigned short* Bsh = (unsigned short*)buf; // [128 w][72]
    {   // stage Zs: 1024 float4, 4 per thread, coalesced
        const float4* src = (const float4*)(Zmix + (long)bo * 2048);
        float4* dst = (float4*)Zs;
#pragma unroll
        for (int p = 0; p < 4; ++p) dst[t + p * 256] = src[t + p * 256];
    }
    __syncthreads();
    // C1: thread owns (h1 = t&127, yh = t>>7 -> 16 ky)
    int h1 = t & 127, yh = t >> 7;
    int h = hb * 128 + h1;
    float2 st = tw[h];
    float C = st.x, S = st.y;
    float gr[16], gi[16];
#pragma unroll
    for (int k = 0; k < 16; ++k) { gr[k] = 0.f; gi[k] = 0.f; }
    float cr = 1.f, ci = 0.f;
    for (int hf = 0; hf < 2; ++hf) {
        if (hf) { float2 s2 = tw[(224 * h) & 255]; cr = s2.x; ci = s2.y; }
        for (int mm = 0; mm < 32; ++mm) {
            int m = hf * 32 + mm;
#pragma unroll
            for (int kk = 0; kk < 8; ++kk) {
                float4 z = *(const float4*)&Zs[m * 32 + yh * 16 + kk * 2];   // wave-broadcast
                gr[kk*2]   = fmaf(z.x, cr, fmaf(-z.y, ci, gr[kk*2]));
                gi[kk*2]   = fmaf(z.y, cr, fmaf( z.x, ci, gi[kk*2]));
                gr[kk*2+1] = fmaf(z.z, cr, fmaf(-z.w, ci, gr[kk*2+1]));
                gi[kk*2+1] = fmaf(z.w, cr, fmaf( z.z, ci, gi[kk*2+1]));
            }
            float nc = fmaf(cr, C, -ci * S);
            ci = fmaf(ci, C, cr * S);
            cr = nc;
        }
    }
    {   // G row (bf16) -> LDS
        unsigned* Gp = (unsigned*)&Gs[h1 * 72 + yh * 32];
#pragma unroll
        for (int k = 0; k < 16; ++k)
            Gp[k] = (unsigned)f2bf(gr[k]) | ((unsigned)f2bf(gi[k]) << 16);
    }
    __syncthreads();   // Gs complete; Zs dead (buf reusable)
    // C2: 4 waves, wave rows wv*32; per phase p: N-half of 128 cols
    int wv = t >> 6, lane = t & 63, m = lane & 15, quad = lane >> 4;
    bf16x8 a[2][2];
#pragma unroll
    for (int ms = 0; ms < 2; ++ms)
#pragma unroll
        for (int kh = 0; kh < 2; ++kh)
            a[ms][kh] = *(const bf16x8*)&Gs[(wv * 32 + ms * 16 + m) * 72 + kh * 32 + quad * 8];
    float bv = bias[bo & 31];
    long rowbase = (long)bo * 256 + hb * 128 + wv * 32;
    for (int p = 0; p < 2; ++p) {
        {   // stage BmC half: rows p*128..p*128+128
            int w = t >> 1, k0 = (t & 1) * 32;
            const uint4* src = (const uint4*)(BmC + (p * 128 + w) * 64 + k0);
            unsigned short* dst = &Bsh[w * 72 + k0];
#pragma unroll
            for (int j = 0; j < 4; ++j) *(uint4*)(dst + j * 8) = src[j];
        }
        __syncthreads();
        f32x4 acc[16] = {};
#pragma unroll
        for (int nt = 0; nt < 8; ++nt) {
            bf16x8 b0 = *(const bf16x8*)&Bsh[(nt * 16 + m) * 72 + quad * 8];
            bf16x8 b1 = *(const bf16x8*)&Bsh[(nt * 16 + m) * 72 + 32 + quad * 8];
#pragma unroll
            for (int ms = 0; ms < 2; ++ms) {
                acc[ms * 8 + nt] = __builtin_amdgcn_mfma_f32_16x16x32_bf16(a[ms][0], b0, acc[ms * 8 + nt], 0, 0, 0);
                acc[ms * 8 + nt] = __builtin_amdgcn_mfma_f32_16x16x32_bf16(a[ms][1], b1, acc[ms * 8 + nt], 0, 0, 0);
            }
        }
#pragma unroll
        for (int ms = 0; ms < 2; ++ms)
#pragma unroll
            for (int nt = 0; nt < 8; ++nt)
#pragma unroll
                for (int r = 0; r < 4; ++r)
                    out[(rowbase + ms * 16 + quad * 4 + r) * 256 + p * 128 + nt * 16 + m] = acc[ms * 8 + nt][r] + bv;
        __syncthreads();   // before restaging Bsh
    }
}

extern "C" void kernel_launch(void* const* d_in, const int* in_sizes, int n_in,
                              void* d_out, int out_size, void* d_ws, size_t ws_size,
                              hipStream_t stream) {
    const float* x    = (const float*)d_in[0];
    const float* w1r  = (const float*)d_in[1];
    const float* w1i  = (const float*)d_in[2];
    const float* w2r  = (const float*)d_in[3];
    const float* w2i  = (const float*)d_in[4];
    const float* bias = (const float*)d_in[5];

    char* ws = (char*)d_ws;
    float2* tw             = (float2*)(ws);                                  // 2 KB (slot 4KB)
    float2* wpack          = (float2*)(ws + 4096);                           // 16 MB
    unsigned short* BmA    = (unsigned short*)(ws + 4096 + (16l << 20));     // 32 KB
    unsigned short* BmC    = BmA + 64 * 256;                                 // 32 KB
    float2* Z              = (float2*)(ws + 4096 + (16l << 20) + 65536);     // 4 MB
    float2* Zmix           = (float2*)((char*)Z + (4l << 20));               // 4 MB
    float* out             = (float*)d_out;

    k_setup <<<1 + 128 + 512, BD, 0, stream>>>(tw, BmA, BmC, w1r, w1i, w2r, w2i, wpack);
    k_fftA  <<<256, 512, 0, stream>>>(x, BmA, tw, Z);
    k_mix   <<<512, BD, 0, stream>>>(Z, wpack, Zmix);
    k_fftC  <<<512, BD, 0, stream>>>(Zmix, tw, BmC, bias, out);
}